// Round 7
// baseline (1082.770 us; speedup 1.0000x reference)
//
#include <hip/hip_runtime.h>

#define EPS 1e-5f

typedef __attribute__((ext_vector_type(8))) short short8v;
typedef __attribute__((ext_vector_type(4))) float f32x4;

__device__ __forceinline__ unsigned short f2bf(float f) {
    unsigned u = __builtin_bit_cast(unsigned, f);
    u += 0x7fffu + ((u >> 16) & 1u);
    return (unsigned short)(u >> 16);
}
__device__ __forceinline__ float bf2f(unsigned short h) {
    return __builtin_bit_cast(float, (unsigned)h << 16);
}

// ---------------- zero workspace (float4) ----------------
__global__ __launch_bounds__(256) void zero_kernel(float* __restrict__ p, long n) {
    long i = (long)blockIdx.x * blockDim.x + threadIdx.x;
    long stride = (long)gridDim.x * blockDim.x;
    long n4 = n >> 2;
    float4* p4 = (float4*)p;
    for (long k = i; k < n4; k += stride) p4[k] = make_float4(0.f, 0.f, 0.f, 0.f);
    for (long k = (n4 << 2) + i; k < n; k += stride) p[k] = 0.f;
}

// ---------------- convert x_h (fp32) -> xbf (bf16) ----------------
__global__ __launch_bounds__(256) void xconv_kernel(const float* __restrict__ x,
                                                    unsigned short* __restrict__ xbf, long n8) {
    long i = (long)blockIdx.x * blockDim.x + threadIdx.x;
    long stride = (long)gridDim.x * blockDim.x;
    const float4* x4 = (const float4*)x;
    for (long k = i; k < n8; k += stride) {
        float4 a = x4[2 * k], b = x4[2 * k + 1];
        short8v v;
        v[0] = (short)f2bf(a.x); v[1] = (short)f2bf(a.y);
        v[2] = (short)f2bf(a.z); v[3] = (short)f2bf(a.w);
        v[4] = (short)f2bf(b.x); v[5] = (short)f2bf(b.y);
        v[6] = (short)f2bf(b.z); v[7] = (short)f2bf(b.w);
        ((short8v*)xbf)[k] = v;
    }
}

// ---------------- CSR build: histogram, 2-level scan, permutation scatter ----------------
__global__ __launch_bounds__(256) void hist_kernel(const int* __restrict__ col,
                                                   int* __restrict__ cnt, long E) {
    for (long e = (long)blockIdx.x * 256 + threadIdx.x; e < E; e += (long)gridDim.x * 256)
        atomicAdd(&cnt[col[e]], 1);
}

// 1024 elems/block (256 thr x 4). offs <- block-local exclusive scan; partials[b] <- block sum.
__global__ __launch_bounds__(256) void scan1_kernel(const int* __restrict__ cnt,
                                                    int* __restrict__ offs,
                                                    int* __restrict__ partials, int N) {
    __shared__ int sdata[256];
    int t = threadIdx.x;
    int i0 = blockIdx.x * 1024 + t * 4;
    int c[4]; int tot = 0;
    #pragma unroll
    for (int j = 0; j < 4; ++j) { c[j] = (i0 + j < N) ? cnt[i0 + j] : 0; tot += c[j]; }
    sdata[t] = tot; __syncthreads();
    for (int d = 1; d < 256; d <<= 1) {
        int v = (t >= d) ? sdata[t - d] : 0;
        __syncthreads();
        sdata[t] += v;
        __syncthreads();
    }
    int run = sdata[t] - tot;   // exclusive base for this thread
    #pragma unroll
    for (int j = 0; j < 4; ++j) { if (i0 + j < N) offs[i0 + j] = run; run += c[j]; }
    if (t == 255) partials[blockIdx.x] = sdata[255];
}

// single block: exclusive scan of partials (nb <= 256; N<=262144)
__global__ __launch_bounds__(256) void scan2_kernel(int* __restrict__ partials, int nb) {
    __shared__ int sdata[256];
    int t = threadIdx.x;
    int v = (t < nb) ? partials[t] : 0;
    sdata[t] = v; __syncthreads();
    for (int d = 1; d < 256; d <<= 1) {
        int w = (t >= d) ? sdata[t - d] : 0;
        __syncthreads();
        sdata[t] += w;
        __syncthreads();
    }
    if (t < nb) partials[t] = sdata[t] - v;
}

__global__ __launch_bounds__(256) void scan3_kernel(int* __restrict__ offs,
                                                    int* __restrict__ head,
                                                    const int* __restrict__ partials, int N) {
    int base = partials[blockIdx.x];
    int i0 = blockIdx.x * 1024 + threadIdx.x * 4;
    #pragma unroll
    for (int j = 0; j < 4; ++j) {
        int i = i0 + j;
        if (i < N) { int v = offs[i] + base; offs[i] = v; head[i] = v; }
    }
}

__global__ __launch_bounds__(256) void permscat_kernel(const int* __restrict__ col,
                                                       int* __restrict__ head,
                                                       int* __restrict__ perm, long E) {
    for (long e = (long)blockIdx.x * 256 + threadIdx.x; e < E; e += (long)gridDim.x * 256) {
        int cdst = col[e];
        int pos = atomicAdd(&head[cdst], 1);
        perm[pos] = e;
    }
}

// ---------------- edge stage (MFMA, dst-sorted order via perm, pk_bf16 atomics) ----------------
// One wave per 64 sorted edges: consecutive edges share dst -> atomic writes land on few
// contiguous summed lines that stay resident and merge in L2.
__global__ __launch_bounds__(256) void edge_kernel(
    const unsigned short* __restrict__ xbf, const int* __restrict__ eidx,
    const float* __restrict__ eattr, const int* __restrict__ perm,
    const float* __restrict__ W1, const float* __restrict__ b1,
    const float* __restrict__ g1, const float* __restrict__ be1,
    unsigned short* __restrict__ summed,
    int E, int N)
{
    const int lane = threadIdx.x & 63;
    const int wid  = threadIdx.x >> 6;
    const int c = lane & 15;
    const int q = lane >> 4;

    // B fragments in VGPRs (R4/R5 structure: moderate occupancy beat 8-wave thrash in R6)
    short8v w1f[4][4];
    #pragma unroll
    for (int ks = 0; ks < 4; ++ks) {
        #pragma unroll
        for (int nt = 0; nt < 4; ++nt) {
            int k0 = ks * 32 + q * 8;
            int n  = nt * 16 + c;
            short8v f;
            #pragma unroll
            for (int j = 0; j < 8; ++j) f[j] = (short)f2bf(W1[(k0 + j) * 64 + n]);
            w1f[ks][nt] = f;
        }
    }
    float b1v[4], g1v[4], bev[4];
    #pragma unroll
    for (int nt = 0; nt < 4; ++nt) {
        b1v[nt] = b1[nt * 16 + c];
        g1v[nt] = g1[nt * 16 + c];
        bev[nt] = be1[nt * 16 + c];
    }

    for (long e0 = (long)blockIdx.x * 256 + wid * 64; e0 < E; e0 += (long)gridDim.x * 256) {
        // coalesced loads of this tile's sorted slots: edge id + dst (dst is sorted/contiguous)
        long el = e0 + lane;
        int pe_l  = (el < E) ? perm[el] : 0;
        int col_v = (el < E) ? eidx[E + pe_l] : -1;

        #pragma unroll
        for (int mt = 0; mt < 4; ++mt) {
            int pidx = __shfl(pe_l, mt * 16 + c);
            int src  = eidx[pidx];
            const unsigned short* xp = xbf + (long)src * 64;
            const float* ep = eattr + (long)pidx * 64;

            f32x4 acc[4];
            #pragma unroll
            for (int nt = 0; nt < 4; ++nt) acc[nt] = (f32x4){0.f, 0.f, 0.f, 0.f};

            // ks 0..1: x half (bf16 copy, one 16B frag load)
            #pragma unroll
            for (int ks = 0; ks < 2; ++ks) {
                short8v a = *(const short8v*)(xp + ks * 32 + q * 8);
                #pragma unroll
                for (int nt = 0; nt < 4; ++nt)
                    acc[nt] = __builtin_amdgcn_mfma_f32_16x16x32_bf16(
                        a, w1f[ks][nt], acc[nt], 0, 0, 0);
            }
            // ks 2..3: eattr half (fp32 row gather + convert)
            #pragma unroll
            for (int ks = 2; ks < 4; ++ks) {
                int k0 = (ks - 2) * 32 + q * 8;
                float4 lo = *(const float4*)(ep + k0);
                float4 hi = *(const float4*)(ep + k0 + 4);
                short8v a;
                a[0] = (short)f2bf(lo.x); a[1] = (short)f2bf(lo.y);
                a[2] = (short)f2bf(lo.z); a[3] = (short)f2bf(lo.w);
                a[4] = (short)f2bf(hi.x); a[5] = (short)f2bf(hi.y);
                a[6] = (short)f2bf(hi.z); a[7] = (short)f2bf(hi.w);
                #pragma unroll
                for (int nt = 0; nt < 4; ++nt)
                    acc[nt] = __builtin_amdgcn_mfma_f32_16x16x32_bf16(
                        a, w1f[ks][nt], acc[nt], 0, 0, 0);
            }

            // epilogue: bias + relu + LN (row = edge) + packed-bf16 atomic scatter
            float s1[4] = {0, 0, 0, 0}, s2[4] = {0, 0, 0, 0};
            #pragma unroll
            for (int nt = 0; nt < 4; ++nt) {
                #pragma unroll
                for (int r = 0; r < 4; ++r) {
                    float f = fmaxf(acc[nt][r] + b1v[nt], 0.f);
                    acc[nt][r] = f;
                    s1[r] += f; s2[r] += f * f;
                }
            }
            #pragma unroll
            for (int m = 1; m <= 8; m <<= 1) {
                #pragma unroll
                for (int r = 0; r < 4; ++r) {
                    s1[r] += __shfl_xor(s1[r], m);
                    s2[r] += __shfl_xor(s2[r], m);
                }
            }
            float mu[4], rs[4]; int dst[4];
            #pragma unroll
            for (int r = 0; r < 4; ++r) {
                mu[r] = s1[r] * (1.f / 64.f);
                float var = s2[r] * (1.f / 64.f) - mu[r] * mu[r];
                rs[r] = rsqrtf(var + EPS);
                dst[r] = __shfl(col_v, mt * 16 + q * 4 + r);   // -1 for tail slots
            }
            #pragma unroll
            for (int nt = 0; nt < 4; ++nt) {
                #pragma unroll
                for (int r = 0; r < 4; ++r) {
                    float outv = (acc[nt][r] - mu[r]) * rs[r] * g1v[nt] + bev[nt];
                    float nb = __shfl_xor(outv, 1);
                    if (dst[r] >= 0 && !(c & 1)) {
                        unsigned pk = (unsigned)f2bf(outv) | ((unsigned)f2bf(nb) << 16);
                        unsigned long long a64 = (unsigned long long)
                            (summed + (long)dst[r] * 64 + nt * 16 + c);
                        asm volatile("global_atomic_pk_add_bf16 %0, %1, off"
                                     :: "v"(a64), "v"(pk));
                    }
                }
            }
        }
    }
}

// ---------------- node stage (MFMA; cnt from int histogram) ----------------
__global__ __launch_bounds__(256) void node_kernel(
    const float* __restrict__ x_h, const float* __restrict__ u,
    const float* __restrict__ W2, const float* __restrict__ b2,
    const float* __restrict__ g2, const float* __restrict__ be2,
    const float* __restrict__ W3, const float* __restrict__ b3,
    const float* __restrict__ g3, const float* __restrict__ be3,
    const unsigned short* __restrict__ summed, const int* __restrict__ cnt,
    float* __restrict__ out, int N)
{
    __shared__ unsigned short sh[4][64][72];

    const int lane = threadIdx.x & 63;
    const int wid  = threadIdx.x >> 6;
    const int c = lane & 15;
    const int q = lane >> 4;
    const float u0 = u[0];

    short8v w2f[4][4], w3f[2][4];
    #pragma unroll
    for (int ks = 0; ks < 4; ++ks)
        #pragma unroll
        for (int nt = 0; nt < 4; ++nt) {
            int k0 = ks * 32 + q * 8;
            int n  = nt * 16 + c;
            short8v f;
            #pragma unroll
            for (int j = 0; j < 8; ++j) f[j] = (short)f2bf(W2[(k0 + j) * 64 + n]);
            w2f[ks][nt] = f;
        }
    #pragma unroll
    for (int ks = 0; ks < 2; ++ks)
        #pragma unroll
        for (int nt = 0; nt < 4; ++nt) {
            int k0 = ks * 32 + q * 8;
            int n  = nt * 16 + c;
            short8v f;
            #pragma unroll
            for (int j = 0; j < 8; ++j) f[j] = (short)f2bf(W3[(k0 + j) * 64 + n]);
            w3f[ks][nt] = f;
        }

    float b2p[4], g2v[4], be2v[4], b3v[4], g3v[4], be3v[4];
    #pragma unroll
    for (int nt = 0; nt < 4; ++nt) {
        int n = nt * 16 + c;
        b2p[nt] = b2[n] + u0 * W2[128 * 64 + n];
        g2v[nt] = g2[n]; be2v[nt] = be2[n];
        b3v[nt] = b3[n]; g3v[nt] = g3[n]; be3v[nt] = be3[n];
    }

    const long n0 = ((long)blockIdx.x * 4 + wid) * 64;
    if (n0 >= N) return;

    #pragma unroll
    for (int mt = 0; mt < 4; ++mt) {
        long nr = n0 + mt * 16 + c;
        long nc = (nr < N) ? nr : (N - 1);
        const float* xp = x_h + nc * 64;
        const unsigned short* sp = summed + nc * 64;
        float inv = 1.f / fmaxf((float)cnt[nc], 1.f);

        f32x4 acc[4];
        #pragma unroll
        for (int nt = 0; nt < 4; ++nt) acc[nt] = (f32x4){0.f, 0.f, 0.f, 0.f};

        #pragma unroll
        for (int ks = 0; ks < 4; ++ks) {
            int k0 = ks * 32 + q * 8;
            short8v a;
            if (ks < 2) {
                float4 lo = *(const float4*)(xp + k0);
                float4 hi = *(const float4*)(xp + k0 + 4);
                a[0] = (short)f2bf(lo.x); a[1] = (short)f2bf(lo.y);
                a[2] = (short)f2bf(lo.z); a[3] = (short)f2bf(lo.w);
                a[4] = (short)f2bf(hi.x); a[5] = (short)f2bf(hi.y);
                a[6] = (short)f2bf(hi.z); a[7] = (short)f2bf(hi.w);
            } else {
                short8v raw = *(const short8v*)(sp + (k0 - 64));
                #pragma unroll
                for (int j = 0; j < 8; ++j)
                    a[j] = (short)f2bf(bf2f((unsigned short)raw[j]) * inv);
            }
            #pragma unroll
            for (int nt = 0; nt < 4; ++nt)
                acc[nt] = __builtin_amdgcn_mfma_f32_16x16x32_bf16(a, w2f[ks][nt], acc[nt], 0, 0, 0);
        }

        float s1[4] = {0, 0, 0, 0}, s2[4] = {0, 0, 0, 0};
        #pragma unroll
        for (int nt = 0; nt < 4; ++nt)
            #pragma unroll
            for (int r = 0; r < 4; ++r) {
                float f = fmaxf(acc[nt][r] + b2p[nt], 0.f);
                acc[nt][r] = f;
                s1[r] += f; s2[r] += f * f;
            }
        #pragma unroll
        for (int m = 1; m <= 8; m <<= 1)
            #pragma unroll
            for (int r = 0; r < 4; ++r) {
                s1[r] += __shfl_xor(s1[r], m);
                s2[r] += __shfl_xor(s2[r], m);
            }
        #pragma unroll
        for (int r = 0; r < 4; ++r) {
            float mu = s1[r] * (1.f / 64.f);
            float var = s2[r] * (1.f / 64.f) - mu * mu;
            float rs = rsqrtf(var + EPS);
            #pragma unroll
            for (int nt = 0; nt < 4; ++nt) {
                float h2 = (acc[nt][r] - mu) * rs * g2v[nt] + be2v[nt];
                sh[wid][mt * 16 + q * 4 + r][nt * 16 + c] = f2bf(h2);
            }
        }
    }

    #pragma unroll
    for (int mt = 0; mt < 4; ++mt) {
        f32x4 acc[4];
        #pragma unroll
        for (int nt = 0; nt < 4; ++nt) acc[nt] = (f32x4){0.f, 0.f, 0.f, 0.f};

        #pragma unroll
        for (int ks = 0; ks < 2; ++ks) {
            short8v a = *(const short8v*)&sh[wid][mt * 16 + c][ks * 32 + q * 8];
            #pragma unroll
            for (int nt = 0; nt < 4; ++nt)
                acc[nt] = __builtin_amdgcn_mfma_f32_16x16x32_bf16(a, w3f[ks][nt], acc[nt], 0, 0, 0);
        }

        float s1[4] = {0, 0, 0, 0}, s2[4] = {0, 0, 0, 0};
        #pragma unroll
        for (int nt = 0; nt < 4; ++nt)
            #pragma unroll
            for (int r = 0; r < 4; ++r) {
                float f = acc[nt][r] + b3v[nt];
                acc[nt][r] = f;
                s1[r] += f; s2[r] += f * f;
            }
        #pragma unroll
        for (int m = 1; m <= 8; m <<= 1)
            #pragma unroll
            for (int r = 0; r < 4; ++r) {
                s1[r] += __shfl_xor(s1[r], m);
                s2[r] += __shfl_xor(s2[r], m);
            }
        #pragma unroll
        for (int r = 0; r < 4; ++r) {
            float mu = s1[r] * (1.f / 64.f);
            float var = s2[r] * (1.f / 64.f) - mu * mu;
            float rs = rsqrtf(var + EPS);
            long node = n0 + mt * 16 + q * 4 + r;
            if (node < N) {
                #pragma unroll
                for (int nt = 0; nt < 4; ++nt) {
                    long off = node * 64 + nt * 16 + c;
                    float h3 = (acc[nt][r] - mu) * rs * g3v[nt] + be3v[nt];
                    out[off] = h3 + x_h[off];
                }
            }
        }
    }
}

extern "C" void kernel_launch(void* const* d_in, const int* in_sizes, int n_in,
                              void* d_out, int out_size, void* d_ws, size_t ws_size,
                              hipStream_t stream)
{
    const float* x_h   = (const float*)d_in[0];
    const int*   eidx  = (const int*)  d_in[1];
    const float* eattr = (const float*)d_in[2];
    const float* u     = (const float*)d_in[3];
    // d_in[4] = batch (all zeros, B=1) -> unused
    const float* W1  = (const float*)d_in[5];
    const float* b1  = (const float*)d_in[6];
    const float* g1  = (const float*)d_in[7];
    const float* be1 = (const float*)d_in[8];
    const float* W2  = (const float*)d_in[9];
    const float* b2  = (const float*)d_in[10];
    const float* g2  = (const float*)d_in[11];
    const float* be2 = (const float*)d_in[12];
    const float* W3  = (const float*)d_in[13];
    const float* b3  = (const float*)d_in[14];
    const float* g3  = (const float*)d_in[15];
    const float* be3 = (const float*)d_in[16];

    const int N = in_sizes[0] / 64;
    const int E = in_sizes[1] / 2;
    const int* col = eidx + E;     // destination array

    // workspace: xbf[N*128B] | summed[N*128B] | cnt[N*4] | offs[N*4] | head[N*4] | perm[E*4] | partials[1KB]
    char* w = (char*)d_ws;
    unsigned short* xbf    = (unsigned short*)w;               w += (size_t)N * 128;
    unsigned short* summed = (unsigned short*)w;               w += (size_t)N * 128;
    int* cnt      = (int*)w;                                   w += (size_t)N * 4;
    int* offs     = (int*)w;                                   w += (size_t)N * 4;
    int* head     = (int*)w;                                   w += (size_t)N * 4;
    int* perm     = (int*)w;                                   w += (size_t)E * 4;
    int* partials = (int*)w;

    // zero summed (N*32 floats) + cnt (N ints) — contiguous region
    zero_kernel<<<1024, 256, 0, stream>>>((float*)summed, (long)N * 33);
    xconv_kernel<<<512, 256, 0, stream>>>(x_h, xbf, (long)N * 8);

    // CSR build
    hist_kernel<<<2048, 256, 0, stream>>>(col, cnt, E);
    int sblocks = (N + 1023) / 1024;
    scan1_kernel<<<sblocks, 256, 0, stream>>>(cnt, offs, partials, N);
    scan2_kernel<<<1, 256, 0, stream>>>(partials, sblocks);
    scan3_kernel<<<sblocks, 256, 0, stream>>>(offs, head, partials, N);
    permscat_kernel<<<2048, 256, 0, stream>>>(col, head, perm, E);

    edge_kernel<<<2048, 256, 0, stream>>>(xbf, eidx, eattr, perm, W1, b1, g1, be1,
                                          summed, E, N);

    int nblocks = (N + 255) / 256;
    node_kernel<<<nblocks, 256, 0, stream>>>(x_h, u, W2, b2, g2, be2, W3, b3, g3, be3,
                                             summed, cnt, (float*)d_out, N);
}

// Round 8
// 372.114 us; speedup vs baseline: 2.9098x; 2.9098x over previous
//
#include <hip/hip_runtime.h>

#define EPS 1e-5f

typedef __attribute__((ext_vector_type(8))) short short8v;
typedef __attribute__((ext_vector_type(4))) float f32x4;

__device__ __forceinline__ unsigned short f2bf(float f) {
    unsigned u = __builtin_bit_cast(unsigned, f);
    u += 0x7fffu + ((u >> 16) & 1u);
    return (unsigned short)(u >> 16);
}
__device__ __forceinline__ float bf2f(unsigned short h) {
    return __builtin_bit_cast(float, (unsigned)h << 16);
}

// ---------------- zero workspace (float4) ----------------
__global__ __launch_bounds__(256) void zero_kernel(float* __restrict__ p, long n) {
    long i = (long)blockIdx.x * blockDim.x + threadIdx.x;
    long stride = (long)gridDim.x * blockDim.x;
    long n4 = n >> 2;
    float4* p4 = (float4*)p;
    for (long k = i; k < n4; k += stride) p4[k] = make_float4(0.f, 0.f, 0.f, 0.f);
    for (long k = (n4 << 2) + i; k < n; k += stride) p[k] = 0.f;
}

// ---------------- convert x_h (fp32) -> xbf (bf16) ----------------
__global__ __launch_bounds__(256) void xconv_kernel(const float* __restrict__ x,
                                                    unsigned short* __restrict__ xbf, long n8) {
    long i = (long)blockIdx.x * blockDim.x + threadIdx.x;
    long stride = (long)gridDim.x * blockDim.x;
    const float4* x4 = (const float4*)x;
    for (long k = i; k < n8; k += stride) {
        float4 a = x4[2 * k], b = x4[2 * k + 1];
        short8v v;
        v[0] = (short)f2bf(a.x); v[1] = (short)f2bf(a.y);
        v[2] = (short)f2bf(a.z); v[3] = (short)f2bf(a.w);
        v[4] = (short)f2bf(b.x); v[5] = (short)f2bf(b.y);
        v[6] = (short)f2bf(b.z); v[7] = (short)f2bf(b.w);
        ((short8v*)xbf)[k] = v;
    }
}

// ---------------- CSR build ----------------
__global__ __launch_bounds__(256) void hist_kernel(const int* __restrict__ col,
                                                   int* __restrict__ cnt, long E) {
    for (long e = (long)blockIdx.x * 256 + threadIdx.x; e < E; e += (long)gridDim.x * 256)
        atomicAdd(&cnt[col[e]], 1);
}

__global__ __launch_bounds__(256) void scan1_kernel(const int* __restrict__ cnt,
                                                    int* __restrict__ offs,
                                                    int* __restrict__ partials, int N) {
    __shared__ int sdata[256];
    int t = threadIdx.x;
    int i0 = blockIdx.x * 1024 + t * 4;
    int c[4]; int tot = 0;
    #pragma unroll
    for (int j = 0; j < 4; ++j) { c[j] = (i0 + j < N) ? cnt[i0 + j] : 0; tot += c[j]; }
    sdata[t] = tot; __syncthreads();
    for (int d = 1; d < 256; d <<= 1) {
        int v = (t >= d) ? sdata[t - d] : 0;
        __syncthreads();
        sdata[t] += v;
        __syncthreads();
    }
    int run = sdata[t] - tot;
    #pragma unroll
    for (int j = 0; j < 4; ++j) { if (i0 + j < N) offs[i0 + j] = run; run += c[j]; }
    if (t == 255) partials[blockIdx.x] = sdata[255];
}

__global__ __launch_bounds__(256) void scan2_kernel(int* __restrict__ partials, int nb) {
    __shared__ int sdata[256];
    int t = threadIdx.x;
    int v = (t < nb) ? partials[t] : 0;
    sdata[t] = v; __syncthreads();
    for (int d = 1; d < 256; d <<= 1) {
        int w = (t >= d) ? sdata[t - d] : 0;
        __syncthreads();
        sdata[t] += w;
        __syncthreads();
    }
    if (t < nb) partials[t] = sdata[t] - v;
}

__global__ __launch_bounds__(256) void scan3_kernel(int* __restrict__ offs,
                                                    int* __restrict__ head,
                                                    const int* __restrict__ partials, int N) {
    int base = partials[blockIdx.x];
    int i0 = blockIdx.x * 1024 + threadIdx.x * 4;
    #pragma unroll
    for (int j = 0; j < 4; ++j) {
        int i = i0 + j;
        if (i < N) { int v = offs[i] + base; offs[i] = v; head[i] = v; }
    }
}

// scatter sorted-order arrays: edge id, src row, dst (so edge kernel has coalesced
// loads and only a 2-level gather chain)
__global__ __launch_bounds__(256) void permscat_kernel(const int* __restrict__ row,
                                                       const int* __restrict__ col,
                                                       int* __restrict__ head,
                                                       int* __restrict__ perm,
                                                       int* __restrict__ srcs,
                                                       int* __restrict__ dsts, long E) {
    for (long e = (long)blockIdx.x * 256 + threadIdx.x; e < E; e += (long)gridDim.x * 256) {
        int cdst = col[e];
        int pos = atomicAdd(&head[cdst], 1);
        perm[pos] = (int)e;
        srcs[pos] = row[e];
        dsts[pos] = cdst;
    }
}

// ---------------- edge stage: mlp1+LN per edge, in-tile segment-sum via Seg^T MFMA,
// one pk-atomic per distinct dst per tile (~6/tile instead of 64/tile) ----------------
__global__ __launch_bounds__(256) void edge_kernel(
    const unsigned short* __restrict__ xbf, const float* __restrict__ eattr,
    const int* __restrict__ perm, const int* __restrict__ srcs,
    const int* __restrict__ dsts,
    const float* __restrict__ W1, const float* __restrict__ b1,
    const float* __restrict__ g1, const float* __restrict__ be1,
    unsigned short* __restrict__ summed,
    int E, int N)
{
    __shared__ unsigned short T[4][64][72];   // per-wave m-tile, [feature][edge+pad]
    __shared__ int dseg[4][64];               // per-wave: segment rank -> dst id

    const int lane = threadIdx.x & 63;
    const int wid  = threadIdx.x >> 6;
    const int c = lane & 15;
    const int q = lane >> 4;

    short8v w1f[4][4];
    #pragma unroll
    for (int ks = 0; ks < 4; ++ks) {
        #pragma unroll
        for (int nt = 0; nt < 4; ++nt) {
            int k0 = ks * 32 + q * 8;
            int n  = nt * 16 + c;
            short8v f;
            #pragma unroll
            for (int j = 0; j < 8; ++j) f[j] = (short)f2bf(W1[(k0 + j) * 64 + n]);
            w1f[ks][nt] = f;
        }
    }
    float b1v[4], g1v[4], bev[4];
    #pragma unroll
    for (int nt = 0; nt < 4; ++nt) {
        b1v[nt] = b1[nt * 16 + c];
        g1v[nt] = g1[nt * 16 + c];
        bev[nt] = be1[nt * 16 + c];
    }

    for (long e0 = (long)blockIdx.x * 256 + wid * 64; e0 < E; e0 += (long)gridDim.x * 256) {
        long el = e0 + lane;
        bool valid = el < E;
        int pe = valid ? perm[el] : 0;
        int sv = valid ? srcs[el] : 0;
        int dv = valid ? dsts[el] : -1;     // tail slots form their own (skipped) segment

        // segment boundaries + ranks over the 64 sorted slots (tile-local)
        int prev = __shfl_up(dv, 1);
        int seg  = (lane > 0 && dv != prev) ? 1 : 0;
        int rank = seg;
        #pragma unroll
        for (int d = 1; d < 64; d <<= 1) {
            int v = __shfl_up(rank, d);
            if (lane >= d) rank += v;
        }
        int nseg = __shfl(rank, 63) + 1;
        if (lane == 0 || seg) dseg[wid][rank] = dv;

        // ---- phase 1: mlp1 + LN -> T[feature][edge] ----
        #pragma unroll
        for (int mt = 0; mt < 4; ++mt) {
            int src  = __shfl(sv, mt * 16 + c);
            int pidx = __shfl(pe, mt * 16 + c);
            const unsigned short* xp = xbf + (long)src * 64;
            const float* ep = eattr + (long)pidx * 64;

            f32x4 acc[4];
            #pragma unroll
            for (int nt = 0; nt < 4; ++nt) acc[nt] = (f32x4){0.f, 0.f, 0.f, 0.f};

            #pragma unroll
            for (int ks = 0; ks < 2; ++ks) {
                short8v a = *(const short8v*)(xp + ks * 32 + q * 8);
                #pragma unroll
                for (int nt = 0; nt < 4; ++nt)
                    acc[nt] = __builtin_amdgcn_mfma_f32_16x16x32_bf16(
                        a, w1f[ks][nt], acc[nt], 0, 0, 0);
            }
            #pragma unroll
            for (int ks = 2; ks < 4; ++ks) {
                int k0 = (ks - 2) * 32 + q * 8;
                float4 lo = *(const float4*)(ep + k0);
                float4 hi = *(const float4*)(ep + k0 + 4);
                short8v a;
                a[0] = (short)f2bf(lo.x); a[1] = (short)f2bf(lo.y);
                a[2] = (short)f2bf(lo.z); a[3] = (short)f2bf(lo.w);
                a[4] = (short)f2bf(hi.x); a[5] = (short)f2bf(hi.y);
                a[6] = (short)f2bf(hi.z); a[7] = (short)f2bf(hi.w);
                #pragma unroll
                for (int nt = 0; nt < 4; ++nt)
                    acc[nt] = __builtin_amdgcn_mfma_f32_16x16x32_bf16(
                        a, w1f[ks][nt], acc[nt], 0, 0, 0);
            }

            float s1[4] = {0, 0, 0, 0}, s2[4] = {0, 0, 0, 0};
            #pragma unroll
            for (int nt = 0; nt < 4; ++nt)
                #pragma unroll
                for (int r = 0; r < 4; ++r) {
                    float f = fmaxf(acc[nt][r] + b1v[nt], 0.f);
                    acc[nt][r] = f;
                    s1[r] += f; s2[r] += f * f;
                }
            #pragma unroll
            for (int m = 1; m <= 8; m <<= 1)
                #pragma unroll
                for (int r = 0; r < 4; ++r) {
                    s1[r] += __shfl_xor(s1[r], m);
                    s2[r] += __shfl_xor(s2[r], m);
                }
            #pragma unroll
            for (int r = 0; r < 4; ++r) {
                float mu = s1[r] * (1.f / 64.f);
                float var = s2[r] * (1.f / 64.f) - mu * mu;
                float rs = rsqrtf(var + EPS);
                #pragma unroll
                for (int nt = 0; nt < 4; ++nt) {
                    float h = (acc[nt][r] - mu) * rs * g1v[nt] + bev[nt];
                    T[wid][nt * 16 + c][mt * 16 + q * 4 + r] = f2bf(h);
                }
            }
        }

        // ---- phase 2: segment-sum = Seg^T @ M via MFMA; emit one atomic per segment ----
        short8v bfr[2][4];
        #pragma unroll
        for (int ks = 0; ks < 2; ++ks)
            #pragma unroll
            for (int nt = 0; nt < 4; ++nt)
                bfr[ks][nt] = *(const short8v*)&T[wid][nt * 16 + c][ks * 32 + q * 8];

        const short ONE = (short)0x3F80;   // bf16 1.0
        #pragma unroll
        for (int mt = 0; mt < 4; ++mt) {
            if (mt * 16 < nseg) {          // usually only mt=0 (nseg ~ 6)
                f32x4 acc2[4];
                #pragma unroll
                for (int nt = 0; nt < 4; ++nt) acc2[nt] = (f32x4){0.f, 0.f, 0.f, 0.f};

                #pragma unroll
                for (int ks = 0; ks < 2; ++ks) {
                    short8v af;
                    #pragma unroll
                    for (int j = 0; j < 8; ++j) {
                        int rk = __shfl(rank, ks * 32 + q * 8 + j);
                        af[j] = (rk == mt * 16 + c) ? ONE : (short)0;
                    }
                    #pragma unroll
                    for (int nt = 0; nt < 4; ++nt)
                        acc2[nt] = __builtin_amdgcn_mfma_f32_16x16x32_bf16(
                            af, bfr[ks][nt], acc2[nt], 0, 0, 0);
                }

                #pragma unroll
                for (int r = 0; r < 4; ++r) {
                    int s = mt * 16 + q * 4 + r;
                    #pragma unroll
                    for (int nt = 0; nt < 4; ++nt) {
                        float val = acc2[nt][r];
                        float nb = __shfl_xor(val, 1);   // all lanes exec (pair same s)
                        if (s < nseg && !(c & 1)) {
                            int dst = dseg[wid][s];
                            if (dst >= 0) {
                                unsigned pk = (unsigned)f2bf(val) | ((unsigned)f2bf(nb) << 16);
                                unsigned long long a64 = (unsigned long long)
                                    (summed + (long)dst * 64 + nt * 16 + c);
                                asm volatile("global_atomic_pk_add_bf16 %0, %1, off"
                                             :: "v"(a64), "v"(pk));
                            }
                        }
                    }
                }
            }
        }
    }
}

// ---------------- node stage (MFMA; cnt from int histogram) ----------------
__global__ __launch_bounds__(256) void node_kernel(
    const float* __restrict__ x_h, const float* __restrict__ u,
    const float* __restrict__ W2, const float* __restrict__ b2,
    const float* __restrict__ g2, const float* __restrict__ be2,
    const float* __restrict__ W3, const float* __restrict__ b3,
    const float* __restrict__ g3, const float* __restrict__ be3,
    const unsigned short* __restrict__ summed, const int* __restrict__ cnt,
    float* __restrict__ out, int N)
{
    __shared__ unsigned short sh[4][64][72];

    const int lane = threadIdx.x & 63;
    const int wid  = threadIdx.x >> 6;
    const int c = lane & 15;
    const int q = lane >> 4;
    const float u0 = u[0];

    short8v w2f[4][4], w3f[2][4];
    #pragma unroll
    for (int ks = 0; ks < 4; ++ks)
        #pragma unroll
        for (int nt = 0; nt < 4; ++nt) {
            int k0 = ks * 32 + q * 8;
            int n  = nt * 16 + c;
            short8v f;
            #pragma unroll
            for (int j = 0; j < 8; ++j) f[j] = (short)f2bf(W2[(k0 + j) * 64 + n]);
            w2f[ks][nt] = f;
        }
    #pragma unroll
    for (int ks = 0; ks < 2; ++ks)
        #pragma unroll
        for (int nt = 0; nt < 4; ++nt) {
            int k0 = ks * 32 + q * 8;
            int n  = nt * 16 + c;
            short8v f;
            #pragma unroll
            for (int j = 0; j < 8; ++j) f[j] = (short)f2bf(W3[(k0 + j) * 64 + n]);
            w3f[ks][nt] = f;
        }

    float b2p[4], g2v[4], be2v[4], b3v[4], g3v[4], be3v[4];
    #pragma unroll
    for (int nt = 0; nt < 4; ++nt) {
        int n = nt * 16 + c;
        b2p[nt] = b2[n] + u0 * W2[128 * 64 + n];
        g2v[nt] = g2[n]; be2v[nt] = be2[n];
        b3v[nt] = b3[n]; g3v[nt] = g3[n]; be3v[nt] = be3[n];
    }

    const long n0 = ((long)blockIdx.x * 4 + wid) * 64;
    if (n0 >= N) return;

    #pragma unroll
    for (int mt = 0; mt < 4; ++mt) {
        long nr = n0 + mt * 16 + c;
        long nc = (nr < N) ? nr : (N - 1);
        const float* xp = x_h + nc * 64;
        const unsigned short* sp = summed + nc * 64;
        float inv = 1.f / fmaxf((float)cnt[nc], 1.f);

        f32x4 acc[4];
        #pragma unroll
        for (int nt = 0; nt < 4; ++nt) acc[nt] = (f32x4){0.f, 0.f, 0.f, 0.f};

        #pragma unroll
        for (int ks = 0; ks < 4; ++ks) {
            int k0 = ks * 32 + q * 8;
            short8v a;
            if (ks < 2) {
                float4 lo = *(const float4*)(xp + k0);
                float4 hi = *(const float4*)(xp + k0 + 4);
                a[0] = (short)f2bf(lo.x); a[1] = (short)f2bf(lo.y);
                a[2] = (short)f2bf(lo.z); a[3] = (short)f2bf(lo.w);
                a[4] = (short)f2bf(hi.x); a[5] = (short)f2bf(hi.y);
                a[6] = (short)f2bf(hi.z); a[7] = (short)f2bf(hi.w);
            } else {
                short8v raw = *(const short8v*)(sp + (k0 - 64));
                #pragma unroll
                for (int j = 0; j < 8; ++j)
                    a[j] = (short)f2bf(bf2f((unsigned short)raw[j]) * inv);
            }
            #pragma unroll
            for (int nt = 0; nt < 4; ++nt)
                acc[nt] = __builtin_amdgcn_mfma_f32_16x16x32_bf16(a, w2f[ks][nt], acc[nt], 0, 0, 0);
        }

        float s1[4] = {0, 0, 0, 0}, s2[4] = {0, 0, 0, 0};
        #pragma unroll
        for (int nt = 0; nt < 4; ++nt)
            #pragma unroll
            for (int r = 0; r < 4; ++r) {
                float f = fmaxf(acc[nt][r] + b2p[nt], 0.f);
                acc[nt][r] = f;
                s1[r] += f; s2[r] += f * f;
            }
        #pragma unroll
        for (int m = 1; m <= 8; m <<= 1)
            #pragma unroll
            for (int r = 0; r < 4; ++r) {
                s1[r] += __shfl_xor(s1[r], m);
                s2[r] += __shfl_xor(s2[r], m);
            }
        #pragma unroll
        for (int r = 0; r < 4; ++r) {
            float mu = s1[r] * (1.f / 64.f);
            float var = s2[r] * (1.f / 64.f) - mu * mu;
            float rs = rsqrtf(var + EPS);
            #pragma unroll
            for (int nt = 0; nt < 4; ++nt) {
                float h2 = (acc[nt][r] - mu) * rs * g2v[nt] + be2v[nt];
                sh[wid][mt * 16 + q * 4 + r][nt * 16 + c] = f2bf(h2);
            }
        }
    }

    #pragma unroll
    for (int mt = 0; mt < 4; ++mt) {
        f32x4 acc[4];
        #pragma unroll
        for (int nt = 0; nt < 4; ++nt) acc[nt] = (f32x4){0.f, 0.f, 0.f, 0.f};

        #pragma unroll
        for (int ks = 0; ks < 2; ++ks) {
            short8v a = *(const short8v*)&sh[wid][mt * 16 + c][ks * 32 + q * 8];
            #pragma unroll
            for (int nt = 0; nt < 4; ++nt)
                acc[nt] = __builtin_amdgcn_mfma_f32_16x16x32_bf16(a, w3f[ks][nt], acc[nt], 0, 0, 0);
        }

        float s1[4] = {0, 0, 0, 0}, s2[4] = {0, 0, 0, 0};
        #pragma unroll
        for (int nt = 0; nt < 4; ++nt)
            #pragma unroll
            for (int r = 0; r < 4; ++r) {
                float f = acc[nt][r] + b3v[nt];
                acc[nt][r] = f;
                s1[r] += f; s2[r] += f * f;
            }
        #pragma unroll
        for (int m = 1; m <= 8; m <<= 1)
            #pragma unroll
            for (int r = 0; r < 4; ++r) {
                s1[r] += __shfl_xor(s1[r], m);
                s2[r] += __shfl_xor(s2[r], m);
            }
        #pragma unroll
        for (int r = 0; r < 4; ++r) {
            float mu = s1[r] * (1.f / 64.f);
            float var = s2[r] * (1.f / 64.f) - mu * mu;
            float rs = rsqrtf(var + EPS);
            long node = n0 + mt * 16 + q * 4 + r;
            if (node < N) {
                #pragma unroll
                for (int nt = 0; nt < 4; ++nt) {
                    long off = node * 64 + nt * 16 + c;
                    float h3 = (acc[nt][r] - mu) * rs * g3v[nt] + be3v[nt];
                    out[off] = h3 + x_h[off];
                }
            }
        }
    }
}

extern "C" void kernel_launch(void* const* d_in, const int* in_sizes, int n_in,
                              void* d_out, int out_size, void* d_ws, size_t ws_size,
                              hipStream_t stream)
{
    const float* x_h   = (const float*)d_in[0];
    const int*   eidx  = (const int*)  d_in[1];
    const float* eattr = (const float*)d_in[2];
    const float* u     = (const float*)d_in[3];
    // d_in[4] = batch (all zeros, B=1) -> unused
    const float* W1  = (const float*)d_in[5];
    const float* b1  = (const float*)d_in[6];
    const float* g1  = (const float*)d_in[7];
    const float* be1 = (const float*)d_in[8];
    const float* W2  = (const float*)d_in[9];
    const float* b2  = (const float*)d_in[10];
    const float* g2  = (const float*)d_in[11];
    const float* be2 = (const float*)d_in[12];
    const float* W3  = (const float*)d_in[13];
    const float* b3  = (const float*)d_in[14];
    const float* g3  = (const float*)d_in[15];
    const float* be3 = (const float*)d_in[16];

    const int N = in_sizes[0] / 64;
    const int E = in_sizes[1] / 2;
    const int* row = eidx;
    const int* col = eidx + E;

    // ws: xbf[N*128B] | summed[N*128B] | cnt,offs,head[N*4 each] | perm,srcs,dsts[E*4 each] | partials
    char* w = (char*)d_ws;
    unsigned short* xbf    = (unsigned short*)w;   w += (size_t)N * 128;
    unsigned short* summed = (unsigned short*)w;   w += (size_t)N * 128;
    int* cnt      = (int*)w;                       w += (size_t)N * 4;
    int* offs     = (int*)w;                       w += (size_t)N * 4;
    int* head     = (int*)w;                       w += (size_t)N * 4;
    int* perm     = (int*)w;                       w += (size_t)E * 4;
    int* srcs     = (int*)w;                       w += (size_t)E * 4;
    int* dsts     = (int*)w;                       w += (size_t)E * 4;
    int* partials = (int*)w;

    // zero summed (N*32 floats) + cnt (N ints) — contiguous
    zero_kernel<<<1024, 256, 0, stream>>>((float*)summed, (long)N * 33);
    xconv_kernel<<<512, 256, 0, stream>>>(x_h, xbf, (long)N * 8);

    hist_kernel<<<2048, 256, 0, stream>>>(col, cnt, E);
    int sblocks = (N + 1023) / 1024;
    scan1_kernel<<<sblocks, 256, 0, stream>>>(cnt, offs, partials, N);
    scan2_kernel<<<1, 256, 0, stream>>>(partials, sblocks);
    scan3_kernel<<<sblocks, 256, 0, stream>>>(offs, head, partials, N);
    permscat_kernel<<<2048, 256, 0, stream>>>(row, col, head, perm, srcs, dsts, E);

    edge_kernel<<<2048, 256, 0, stream>>>(xbf, eattr, perm, srcs, dsts,
                                          W1, b1, g1, be1, summed, E, N);

    int nblocks = (N + 255) / 256;
    node_kernel<<<nblocks, 256, 0, stream>>>(x_h, u, W2, b2, g2, be2, W3, b3, g3, be3,
                                             summed, cnt, (float*)d_out, N);
}

// Round 9
// 358.850 us; speedup vs baseline: 3.0173x; 1.0370x over previous
//
#include <hip/hip_runtime.h>

#define EPS 1e-5f

typedef __attribute__((ext_vector_type(8))) short short8v;
typedef __attribute__((ext_vector_type(4))) float f32x4;

__device__ __forceinline__ unsigned short f2bf(float f) {
    unsigned u = __builtin_bit_cast(unsigned, f);
    u += 0x7fffu + ((u >> 16) & 1u);
    return (unsigned short)(u >> 16);
}
__device__ __forceinline__ float bf2f(unsigned short h) {
    return __builtin_bit_cast(float, (unsigned)h << 16);
}

// ---------------- prep: zero summed+cnt AND convert x->bf16 (independent writes) ----------------
__global__ __launch_bounds__(256) void prep_kernel(const float* __restrict__ x,
                                                   unsigned short* __restrict__ xbf,
                                                   float* __restrict__ zbase,
                                                   long zn4, long n8) {
    long i = (long)blockIdx.x * blockDim.x + threadIdx.x;
    long stride = (long)gridDim.x * blockDim.x;
    float4* z4 = (float4*)zbase;
    for (long k = i; k < zn4; k += stride) z4[k] = make_float4(0.f, 0.f, 0.f, 0.f);
    const float4* x4 = (const float4*)x;
    for (long k = i; k < n8; k += stride) {
        float4 a = x4[2 * k], b = x4[2 * k + 1];
        short8v v;
        v[0] = (short)f2bf(a.x); v[1] = (short)f2bf(a.y);
        v[2] = (short)f2bf(a.z); v[3] = (short)f2bf(a.w);
        v[4] = (short)f2bf(b.x); v[5] = (short)f2bf(b.y);
        v[6] = (short)f2bf(b.z); v[7] = (short)f2bf(b.w);
        ((short8v*)xbf)[k] = v;
    }
}

// ---------------- CSR build ----------------
__global__ __launch_bounds__(256) void hist_kernel(const int* __restrict__ col,
                                                   int* __restrict__ cnt, long E) {
    for (long e = (long)blockIdx.x * 256 + threadIdx.x; e < E; e += (long)gridDim.x * 256)
        atomicAdd(&cnt[col[e]], 1);
}

__global__ __launch_bounds__(256) void scan1_kernel(const int* __restrict__ cnt,
                                                    int* __restrict__ offs,
                                                    int* __restrict__ partials, int N) {
    __shared__ int sdata[256];
    int t = threadIdx.x;
    int i0 = blockIdx.x * 1024 + t * 4;
    int c[4]; int tot = 0;
    #pragma unroll
    for (int j = 0; j < 4; ++j) { c[j] = (i0 + j < N) ? cnt[i0 + j] : 0; tot += c[j]; }
    sdata[t] = tot; __syncthreads();
    for (int d = 1; d < 256; d <<= 1) {
        int v = (t >= d) ? sdata[t - d] : 0;
        __syncthreads();
        sdata[t] += v;
        __syncthreads();
    }
    int run = sdata[t] - tot;
    #pragma unroll
    for (int j = 0; j < 4; ++j) { if (i0 + j < N) offs[i0 + j] = run; run += c[j]; }
    if (t == 255) partials[blockIdx.x] = sdata[255];
}

__global__ __launch_bounds__(256) void scan2_kernel(int* __restrict__ partials, int nb) {
    __shared__ int sdata[256];
    int t = threadIdx.x;
    int v = (t < nb) ? partials[t] : 0;
    sdata[t] = v; __syncthreads();
    for (int d = 1; d < 256; d <<= 1) {
        int w = (t >= d) ? sdata[t - d] : 0;
        __syncthreads();
        sdata[t] += w;
        __syncthreads();
    }
    if (t < nb) partials[t] = sdata[t] - v;
}

__global__ __launch_bounds__(256) void scan3_kernel(int* __restrict__ offs,
                                                    int* __restrict__ head,
                                                    const int* __restrict__ partials, int N) {
    int base = partials[blockIdx.x];
    int i0 = blockIdx.x * 1024 + threadIdx.x * 4;
    #pragma unroll
    for (int j = 0; j < 4; ++j) {
        int i = i0 + j;
        if (i < N) { int v = offs[i] + base; offs[i] = v; head[i] = v; }
    }
}

// sorted-order arrays: einfo[pos]=(edge id, src) as one 8B store; dsts[pos]=dst
__global__ __launch_bounds__(256) void permscat_kernel(const int* __restrict__ row,
                                                       const int* __restrict__ col,
                                                       int* __restrict__ head,
                                                       int2* __restrict__ einfo,
                                                       int* __restrict__ dsts, long E) {
    for (long e = (long)blockIdx.x * 256 + threadIdx.x; e < E; e += (long)gridDim.x * 256) {
        int cdst = col[e];
        int pos = atomicAdd(&head[cdst], 1);
        einfo[pos] = make_int2((int)e, row[e]);
        dsts[pos] = cdst;
    }
}

// ---------------- edge stage: mlp1+LN per edge, in-tile segment-sum via Seg^T MFMA,
// one pk-atomic per distinct dst per tile ----------------
__global__ __launch_bounds__(256) void edge_kernel(
    const unsigned short* __restrict__ xbf, const float* __restrict__ eattr,
    const int2* __restrict__ einfo, const int* __restrict__ dsts,
    const float* __restrict__ W1, const float* __restrict__ b1,
    const float* __restrict__ g1, const float* __restrict__ be1,
    unsigned short* __restrict__ summed,
    int E, int N)
{
    __shared__ unsigned short T[4][64][72];   // per-wave m-tile, [feature][edge+pad]
    __shared__ int dseg[4][64];               // per-wave: segment rank -> dst id

    const int lane = threadIdx.x & 63;
    const int wid  = threadIdx.x >> 6;
    const int c = lane & 15;
    const int q = lane >> 4;

    short8v w1f[4][4];
    #pragma unroll
    for (int ks = 0; ks < 4; ++ks) {
        #pragma unroll
        for (int nt = 0; nt < 4; ++nt) {
            int k0 = ks * 32 + q * 8;
            int n  = nt * 16 + c;
            short8v f;
            #pragma unroll
            for (int j = 0; j < 8; ++j) f[j] = (short)f2bf(W1[(k0 + j) * 64 + n]);
            w1f[ks][nt] = f;
        }
    }
    float b1v[4], g1v[4], bev[4];
    #pragma unroll
    for (int nt = 0; nt < 4; ++nt) {
        b1v[nt] = b1[nt * 16 + c];
        g1v[nt] = g1[nt * 16 + c];
        bev[nt] = be1[nt * 16 + c];
    }

    for (long e0 = (long)blockIdx.x * 256 + wid * 64; e0 < E; e0 += (long)gridDim.x * 256) {
        long el = e0 + lane;
        bool valid = el < E;
        int2 ps = valid ? einfo[el] : make_int2(0, 0);
        int pe = ps.x;                       // original edge id (eattr row)
        int sv = ps.y;                       // src node
        int dv = valid ? dsts[el] : -1;      // tail slots form their own (skipped) segment

        // segment boundaries + ranks over the 64 sorted slots (tile-local)
        int prev = __shfl_up(dv, 1);
        int seg  = (lane > 0 && dv != prev) ? 1 : 0;
        int rank = seg;
        #pragma unroll
        for (int d = 1; d < 64; d <<= 1) {
            int v = __shfl_up(rank, d);
            if (lane >= d) rank += v;
        }
        int nseg = __shfl(rank, 63) + 1;
        if (lane == 0 || seg) dseg[wid][rank] = dv;

        // ---- phase 1: mlp1 + LN -> T[feature][edge] ----
        #pragma unroll
        for (int mt = 0; mt < 4; ++mt) {
            int src  = __shfl(sv, mt * 16 + c);
            int pidx = __shfl(pe, mt * 16 + c);
            const unsigned short* xp = xbf + (long)src * 64;
            const float* ep = eattr + (long)pidx * 64;

            f32x4 acc[4];
            #pragma unroll
            for (int nt = 0; nt < 4; ++nt) acc[nt] = (f32x4){0.f, 0.f, 0.f, 0.f};

            #pragma unroll
            for (int ks = 0; ks < 2; ++ks) {
                short8v a = *(const short8v*)(xp + ks * 32 + q * 8);
                #pragma unroll
                for (int nt = 0; nt < 4; ++nt)
                    acc[nt] = __builtin_amdgcn_mfma_f32_16x16x32_bf16(
                        a, w1f[ks][nt], acc[nt], 0, 0, 0);
            }
            #pragma unroll
            for (int ks = 2; ks < 4; ++ks) {
                int k0 = (ks - 2) * 32 + q * 8;
                float4 lo = *(const float4*)(ep + k0);
                float4 hi = *(const float4*)(ep + k0 + 4);
                short8v a;
                a[0] = (short)f2bf(lo.x); a[1] = (short)f2bf(lo.y);
                a[2] = (short)f2bf(lo.z); a[3] = (short)f2bf(lo.w);
                a[4] = (short)f2bf(hi.x); a[5] = (short)f2bf(hi.y);
                a[6] = (short)f2bf(hi.z); a[7] = (short)f2bf(hi.w);
                #pragma unroll
                for (int nt = 0; nt < 4; ++nt)
                    acc[nt] = __builtin_amdgcn_mfma_f32_16x16x32_bf16(
                        a, w1f[ks][nt], acc[nt], 0, 0, 0);
            }

            float s1[4] = {0, 0, 0, 0}, s2[4] = {0, 0, 0, 0};
            #pragma unroll
            for (int nt = 0; nt < 4; ++nt)
                #pragma unroll
                for (int r = 0; r < 4; ++r) {
                    float f = fmaxf(acc[nt][r] + b1v[nt], 0.f);
                    acc[nt][r] = f;
                    s1[r] += f; s2[r] += f * f;
                }
            #pragma unroll
            for (int m = 1; m <= 8; m <<= 1)
                #pragma unroll
                for (int r = 0; r < 4; ++r) {
                    s1[r] += __shfl_xor(s1[r], m);
                    s2[r] += __shfl_xor(s2[r], m);
                }
            #pragma unroll
            for (int r = 0; r < 4; ++r) {
                float mu = s1[r] * (1.f / 64.f);
                float var = s2[r] * (1.f / 64.f) - mu * mu;
                float rs = rsqrtf(var + EPS);
                #pragma unroll
                for (int nt = 0; nt < 4; ++nt) {
                    float h = (acc[nt][r] - mu) * rs * g1v[nt] + bev[nt];
                    T[wid][nt * 16 + c][mt * 16 + q * 4 + r] = f2bf(h);
                }
            }
        }

        // ---- phase 2: segment-sum = Seg^T @ M via MFMA; one atomic per segment ----
        short8v bfr[2][4];
        #pragma unroll
        for (int ks = 0; ks < 2; ++ks)
            #pragma unroll
            for (int nt = 0; nt < 4; ++nt)
                bfr[ks][nt] = *(const short8v*)&T[wid][nt * 16 + c][ks * 32 + q * 8];

        const short ONE = (short)0x3F80;   // bf16 1.0
        #pragma unroll
        for (int mt = 0; mt < 4; ++mt) {
            if (mt * 16 < nseg) {          // usually only mt=0 (nseg ~ 6)
                f32x4 acc2[4];
                #pragma unroll
                for (int nt = 0; nt < 4; ++nt) acc2[nt] = (f32x4){0.f, 0.f, 0.f, 0.f};

                #pragma unroll
                for (int ks = 0; ks < 2; ++ks) {
                    short8v af;
                    #pragma unroll
                    for (int j = 0; j < 8; ++j) {
                        int rk = __shfl(rank, ks * 32 + q * 8 + j);
                        af[j] = (rk == mt * 16 + c) ? ONE : (short)0;
                    }
                    #pragma unroll
                    for (int nt = 0; nt < 4; ++nt)
                        acc2[nt] = __builtin_amdgcn_mfma_f32_16x16x32_bf16(
                            af, bfr[ks][nt], acc2[nt], 0, 0, 0);
                }

                #pragma unroll
                for (int r = 0; r < 4; ++r) {
                    int s = mt * 16 + q * 4 + r;
                    #pragma unroll
                    for (int nt = 0; nt < 4; ++nt) {
                        float val = acc2[nt][r];
                        float nb = __shfl_xor(val, 1);   // all lanes exec (pair same s)
                        if (s < nseg && !(c & 1)) {
                            int dst = dseg[wid][s];
                            if (dst >= 0) {
                                unsigned pk = (unsigned)f2bf(val) | ((unsigned)f2bf(nb) << 16);
                                unsigned long long a64 = (unsigned long long)
                                    (summed + (long)dst * 64 + nt * 16 + c);
                                asm volatile("global_atomic_pk_add_bf16 %0, %1, off"
                                             :: "v"(a64), "v"(pk));
                            }
                        }
                    }
                }
            }
        }
    }
}

// ---------------- node stage (MFMA; cnt from int histogram) ----------------
__global__ __launch_bounds__(256) void node_kernel(
    const float* __restrict__ x_h, const float* __restrict__ u,
    const float* __restrict__ W2, const float* __restrict__ b2,
    const float* __restrict__ g2, const float* __restrict__ be2,
    const float* __restrict__ W3, const float* __restrict__ b3,
    const float* __restrict__ g3, const float* __restrict__ be3,
    const unsigned short* __restrict__ summed, const int* __restrict__ cnt,
    float* __restrict__ out, int N)
{
    __shared__ unsigned short sh[4][64][72];

    const int lane = threadIdx.x & 63;
    const int wid  = threadIdx.x >> 6;
    const int c = lane & 15;
    const int q = lane >> 4;
    const float u0 = u[0];

    short8v w2f[4][4], w3f[2][4];
    #pragma unroll
    for (int ks = 0; ks < 4; ++ks)
        #pragma unroll
        for (int nt = 0; nt < 4; ++nt) {
            int k0 = ks * 32 + q * 8;
            int n  = nt * 16 + c;
            short8v f;
            #pragma unroll
            for (int j = 0; j < 8; ++j) f[j] = (short)f2bf(W2[(k0 + j) * 64 + n]);
            w2f[ks][nt] = f;
        }
    #pragma unroll
    for (int ks = 0; ks < 2; ++ks)
        #pragma unroll
        for (int nt = 0; nt < 4; ++nt) {
            int k0 = ks * 32 + q * 8;
            int n  = nt * 16 + c;
            short8v f;
            #pragma unroll
            for (int j = 0; j < 8; ++j) f[j] = (short)f2bf(W3[(k0 + j) * 64 + n]);
            w3f[ks][nt] = f;
        }

    float b2p[4], g2v[4], be2v[4], b3v[4], g3v[4], be3v[4];
    #pragma unroll
    for (int nt = 0; nt < 4; ++nt) {
        int n = nt * 16 + c;
        b2p[nt] = b2[n] + u0 * W2[128 * 64 + n];
        g2v[nt] = g2[n]; be2v[nt] = be2[n];
        b3v[nt] = b3[n]; g3v[nt] = g3[n]; be3v[nt] = be3[n];
    }

    const long n0 = ((long)blockIdx.x * 4 + wid) * 64;
    if (n0 >= N) return;

    #pragma unroll
    for (int mt = 0; mt < 4; ++mt) {
        long nr = n0 + mt * 16 + c;
        long nc = (nr < N) ? nr : (N - 1);
        const float* xp = x_h + nc * 64;
        const unsigned short* sp = summed + nc * 64;
        float inv = 1.f / fmaxf((float)cnt[nc], 1.f);

        f32x4 acc[4];
        #pragma unroll
        for (int nt = 0; nt < 4; ++nt) acc[nt] = (f32x4){0.f, 0.f, 0.f, 0.f};

        #pragma unroll
        for (int ks = 0; ks < 4; ++ks) {
            int k0 = ks * 32 + q * 8;
            short8v a;
            if (ks < 2) {
                float4 lo = *(const float4*)(xp + k0);
                float4 hi = *(const float4*)(xp + k0 + 4);
                a[0] = (short)f2bf(lo.x); a[1] = (short)f2bf(lo.y);
                a[2] = (short)f2bf(lo.z); a[3] = (short)f2bf(lo.w);
                a[4] = (short)f2bf(hi.x); a[5] = (short)f2bf(hi.y);
                a[6] = (short)f2bf(hi.z); a[7] = (short)f2bf(hi.w);
            } else {
                short8v raw = *(const short8v*)(sp + (k0 - 64));
                #pragma unroll
                for (int j = 0; j < 8; ++j)
                    a[j] = (short)f2bf(bf2f((unsigned short)raw[j]) * inv);
            }
            #pragma unroll
            for (int nt = 0; nt < 4; ++nt)
                acc[nt] = __builtin_amdgcn_mfma_f32_16x16x32_bf16(a, w2f[ks][nt], acc[nt], 0, 0, 0);
        }

        float s1[4] = {0, 0, 0, 0}, s2[4] = {0, 0, 0, 0};
        #pragma unroll
        for (int nt = 0; nt < 4; ++nt)
            #pragma unroll
            for (int r = 0; r < 4; ++r) {
                float f = fmaxf(acc[nt][r] + b2p[nt], 0.f);
                acc[nt][r] = f;
                s1[r] += f; s2[r] += f * f;
            }
        #pragma unroll
        for (int m = 1; m <= 8; m <<= 1)
            #pragma unroll
            for (int r = 0; r < 4; ++r) {
                s1[r] += __shfl_xor(s1[r], m);
                s2[r] += __shfl_xor(s2[r], m);
            }
        #pragma unroll
        for (int r = 0; r < 4; ++r) {
            float mu = s1[r] * (1.f / 64.f);
            float var = s2[r] * (1.f / 64.f) - mu * mu;
            float rs = rsqrtf(var + EPS);
            #pragma unroll
            for (int nt = 0; nt < 4; ++nt) {
                float h2 = (acc[nt][r] - mu) * rs * g2v[nt] + be2v[nt];
                sh[wid][mt * 16 + q * 4 + r][nt * 16 + c] = f2bf(h2);
            }
        }
    }

    #pragma unroll
    for (int mt = 0; mt < 4; ++mt) {
        f32x4 acc[4];
        #pragma unroll
        for (int nt = 0; nt < 4; ++nt) acc[nt] = (f32x4){0.f, 0.f, 0.f, 0.f};

        #pragma unroll
        for (int ks = 0; ks < 2; ++ks) {
            short8v a = *(const short8v*)&sh[wid][mt * 16 + c][ks * 32 + q * 8];
            #pragma unroll
            for (int nt = 0; nt < 4; ++nt)
                acc[nt] = __builtin_amdgcn_mfma_f32_16x16x32_bf16(a, w3f[ks][nt], acc[nt], 0, 0, 0);
        }

        float s1[4] = {0, 0, 0, 0}, s2[4] = {0, 0, 0, 0};
        #pragma unroll
        for (int nt = 0; nt < 4; ++nt)
            #pragma unroll
            for (int r = 0; r < 4; ++r) {
                float f = acc[nt][r] + b3v[nt];
                acc[nt][r] = f;
                s1[r] += f; s2[r] += f * f;
            }
        #pragma unroll
        for (int m = 1; m <= 8; m <<= 1)
            #pragma unroll
            for (int r = 0; r < 4; ++r) {
                s1[r] += __shfl_xor(s1[r], m);
                s2[r] += __shfl_xor(s2[r], m);
            }
        #pragma unroll
        for (int r = 0; r < 4; ++r) {
            float mu = s1[r] * (1.f / 64.f);
            float var = s2[r] * (1.f / 64.f) - mu * mu;
            float rs = rsqrtf(var + EPS);
            long node = n0 + mt * 16 + q * 4 + r;
            if (node < N) {
                #pragma unroll
                for (int nt = 0; nt < 4; ++nt) {
                    long off = node * 64 + nt * 16 + c;
                    float h3 = (acc[nt][r] - mu) * rs * g3v[nt] + be3v[nt];
                    out[off] = h3 + x_h[off];
                }
            }
        }
    }
}

extern "C" void kernel_launch(void* const* d_in, const int* in_sizes, int n_in,
                              void* d_out, int out_size, void* d_ws, size_t ws_size,
                              hipStream_t stream)
{
    const float* x_h   = (const float*)d_in[0];
    const int*   eidx  = (const int*)  d_in[1];
    const float* eattr = (const float*)d_in[2];
    const float* u     = (const float*)d_in[3];
    // d_in[4] = batch (all zeros, B=1) -> unused
    const float* W1  = (const float*)d_in[5];
    const float* b1  = (const float*)d_in[6];
    const float* g1  = (const float*)d_in[7];
    const float* be1 = (const float*)d_in[8];
    const float* W2  = (const float*)d_in[9];
    const float* b2  = (const float*)d_in[10];
    const float* g2  = (const float*)d_in[11];
    const float* be2 = (const float*)d_in[12];
    const float* W3  = (const float*)d_in[13];
    const float* b3  = (const float*)d_in[14];
    const float* g3  = (const float*)d_in[15];
    const float* be3 = (const float*)d_in[16];

    const int N = in_sizes[0] / 64;
    const int E = in_sizes[1] / 2;
    const int* row = eidx;
    const int* col = eidx + E;

    // ws: xbf[N*128B] | summed[N*128B] | cnt,offs,head[N*4 each] | dsts[E*4] | einfo[E*8] | partials
    char* w = (char*)d_ws;
    unsigned short* xbf    = (unsigned short*)w;   w += (size_t)N * 128;
    unsigned short* summed = (unsigned short*)w;   w += (size_t)N * 128;
    int* cnt      = (int*)w;                       w += (size_t)N * 4;
    int* offs     = (int*)w;                       w += (size_t)N * 4;
    int* head     = (int*)w;                       w += (size_t)N * 4;
    int* dsts     = (int*)w;                       w += (size_t)E * 4;
    int2* einfo   = (int2*)w;                      w += (size_t)E * 8;
    int* partials = (int*)w;

    // zero summed (N*32 floats) + cnt (N ints) contiguous, and convert x -> bf16
    prep_kernel<<<1024, 256, 0, stream>>>(x_h, xbf, (float*)summed, ((long)N * 33) / 4, (long)N * 8);

    hist_kernel<<<2048, 256, 0, stream>>>(col, cnt, E);
    int sblocks = (N + 1023) / 1024;
    scan1_kernel<<<sblocks, 256, 0, stream>>>(cnt, offs, partials, N);
    scan2_kernel<<<1, 256, 0, stream>>>(partials, sblocks);
    scan3_kernel<<<sblocks, 256, 0, stream>>>(offs, head, partials, N);
    permscat_kernel<<<2048, 256, 0, stream>>>(row, col, head, einfo, dsts, E);

    // 2 tiles per wave exactly: 18750 tiles / (4 waves/block) / 2
    int tiles = (E + 63) / 64;
    int eblocks = (tiles + 7) / 8;
    edge_kernel<<<eblocks, 256, 0, stream>>>(xbf, eattr, einfo, dsts,
                                             W1, b1, g1, be1, summed, E, N);

    int nblocks = (N + 255) / 256;
    node_kernel<<<nblocks, 256, 0, stream>>>(x_h, u, W2, b2, g2, be2, W3, b3, g3, be3,
                                             summed, cnt, (float*)d_out, N);
}

// Round 10
// 330.827 us; speedup vs baseline: 3.2729x; 1.0847x over previous
//
#include <hip/hip_runtime.h>

#define EPS 1e-5f

typedef __attribute__((ext_vector_type(8))) short short8v;
typedef __attribute__((ext_vector_type(4))) float f32x4;

__device__ __forceinline__ unsigned short f2bf(float f) {
    unsigned u = __builtin_bit_cast(unsigned, f);
    u += 0x7fffu + ((u >> 16) & 1u);
    return (unsigned short)(u >> 16);
}
__device__ __forceinline__ float bf2f(unsigned short h) {
    return __builtin_bit_cast(float, (unsigned)h << 16);
}

// ---------------- prep: zero summed+cnt AND convert x->bf16 ----------------
__global__ __launch_bounds__(256) void prep_kernel(const float* __restrict__ x,
                                                   unsigned short* __restrict__ xbf,
                                                   float* __restrict__ zbase,
                                                   long zn4, long n8) {
    long i = (long)blockIdx.x * blockDim.x + threadIdx.x;
    long stride = (long)gridDim.x * blockDim.x;
    float4* z4 = (float4*)zbase;
    for (long k = i; k < zn4; k += stride) z4[k] = make_float4(0.f, 0.f, 0.f, 0.f);
    const float4* x4 = (const float4*)x;
    for (long k = i; k < n8; k += stride) {
        float4 a = x4[2 * k], b = x4[2 * k + 1];
        short8v v;
        v[0] = (short)f2bf(a.x); v[1] = (short)f2bf(a.y);
        v[2] = (short)f2bf(a.z); v[3] = (short)f2bf(a.w);
        v[4] = (short)f2bf(b.x); v[5] = (short)f2bf(b.y);
        v[6] = (short)f2bf(b.z); v[7] = (short)f2bf(b.w);
        ((short8v*)xbf)[k] = v;
    }
}

// ---------------- fallback-only histogram ----------------
__global__ __launch_bounds__(256) void hist_kernel(const int* __restrict__ col,
                                                   int* __restrict__ cnt, long E) {
    for (long e = (long)blockIdx.x * 256 + threadIdx.x; e < E; e += (long)gridDim.x * 256)
        atomicAdd(&cnt[col[e]], 1);
}

// ---------------- scans ----------------
__global__ __launch_bounds__(256) void scan1_kernel(const int* __restrict__ cnt,
                                                    int* __restrict__ offs,
                                                    int* __restrict__ partials, int N) {
    __shared__ int sdata[256];
    int t = threadIdx.x;
    int i0 = blockIdx.x * 1024 + t * 4;
    int c[4]; int tot = 0;
    #pragma unroll
    for (int j = 0; j < 4; ++j) { c[j] = (i0 + j < N) ? cnt[i0 + j] : 0; tot += c[j]; }
    sdata[t] = tot; __syncthreads();
    for (int d = 1; d < 256; d <<= 1) {
        int v = (t >= d) ? sdata[t - d] : 0;
        __syncthreads();
        sdata[t] += v;
        __syncthreads();
    }
    int run = sdata[t] - tot;
    #pragma unroll
    for (int j = 0; j < 4; ++j) { if (i0 + j < N) offs[i0 + j] = run; run += c[j]; }
    if (t == 255) partials[blockIdx.x] = sdata[255];
}

__global__ __launch_bounds__(256) void scan2_kernel(int* __restrict__ partials, int nb) {
    __shared__ int sdata[256];
    int t = threadIdx.x;
    int v = (t < nb) ? partials[t] : 0;
    sdata[t] = v; __syncthreads();
    for (int d = 1; d < 256; d <<= 1) {
        int w = (t >= d) ? sdata[t - d] : 0;
        __syncthreads();
        sdata[t] += w;
        __syncthreads();
    }
    if (t < nb) partials[t] = sdata[t] - v;
}

__global__ __launch_bounds__(256) void scan3_kernel(int* __restrict__ offs,
                                                    int* __restrict__ head,
                                                    const int* __restrict__ partials, int N) {
    int base = partials[blockIdx.x];
    int i0 = blockIdx.x * 1024 + threadIdx.x * 4;
    #pragma unroll
    for (int j = 0; j < 4; ++j) {
        int i = i0 + j;
        if (i < N) { int v = offs[i] + base; offs[i] = v; head[i] = v; }
    }
}

// ---------------- permutation scatter (new path: perm + dsts) ----------------
__global__ __launch_bounds__(256) void permscat2_kernel(const int* __restrict__ col,
                                                        int* __restrict__ head,
                                                        int* __restrict__ perm,
                                                        int* __restrict__ dsts, long E) {
    for (long e = (long)blockIdx.x * 256 + threadIdx.x; e < E; e += (long)gridDim.x * 256) {
        int cdst = col[e];
        int pos = atomicAdd(&head[cdst], 1);
        perm[pos] = (int)e;
        dsts[pos] = cdst;
    }
}

// ---------------- fallback permscat (einfo + dsts, R9) ----------------
__global__ __launch_bounds__(256) void permscat_r9_kernel(const int* __restrict__ row,
                                                          const int* __restrict__ col,
                                                          int* __restrict__ head,
                                                          int2* __restrict__ einfo,
                                                          int* __restrict__ dsts, long E) {
    for (long e = (long)blockIdx.x * 256 + threadIdx.x; e < E; e += (long)gridDim.x * 256) {
        int cdst = col[e];
        int pos = atomicAdd(&head[cdst], 1);
        einfo[pos] = make_int2((int)e, row[e]);
        dsts[pos] = cdst;
    }
}

// ---------------- K1: natural-order mlp1 + LN -> m[E][64] bf16; fused histogram ----------------
// Streams eattr sequentially (coalesced), gathers xbf rows, no LDS, no sort dependency.
__global__ __launch_bounds__(256) void mlp_kernel(
    const unsigned short* __restrict__ xbf, const int* __restrict__ eidx,
    const float* __restrict__ eattr,
    const float* __restrict__ W1, const float* __restrict__ b1,
    const float* __restrict__ g1, const float* __restrict__ be1,
    unsigned short* __restrict__ m, int* __restrict__ cnt, int E)
{
    const int lane = threadIdx.x & 63;
    const int wid  = threadIdx.x >> 6;
    const int c = lane & 15;
    const int q = lane >> 4;

    short8v w1f[4][4];
    #pragma unroll
    for (int ks = 0; ks < 4; ++ks)
        #pragma unroll
        for (int nt = 0; nt < 4; ++nt) {
            int k0 = ks * 32 + q * 8;
            int n  = nt * 16 + c;
            short8v f;
            #pragma unroll
            for (int j = 0; j < 8; ++j) f[j] = (short)f2bf(W1[(k0 + j) * 64 + n]);
            w1f[ks][nt] = f;
        }
    float b1v[4], g1v[4], bev[4];
    #pragma unroll
    for (int nt = 0; nt < 4; ++nt) {
        b1v[nt] = b1[nt * 16 + c];
        g1v[nt] = g1[nt * 16 + c];
        bev[nt] = be1[nt * 16 + c];
    }

    for (long e0 = (long)blockIdx.x * 256 + wid * 64; e0 < E; e0 += (long)gridDim.x * 256) {
        // fused histogram (coalesced col read, int atomic)
        int sv_l;
        {
            long el = e0 + lane;
            if (el < E) atomicAdd(&cnt[eidx[E + el]], 1);
            sv_l = (el < E) ? eidx[el] : 0;
        }

        #pragma unroll
        for (int mt = 0; mt < 4; ++mt) {
            long er = e0 + mt * 16 + c;
            long ec = (er < E) ? er : (E - 1);
            int src = __shfl(sv_l, mt * 16 + c);
            const unsigned short* xp = xbf + (long)src * 64;
            const float* ep = eattr + ec * 64;

            f32x4 acc[4];
            #pragma unroll
            for (int nt = 0; nt < 4; ++nt) acc[nt] = (f32x4){0.f, 0.f, 0.f, 0.f};

            #pragma unroll
            for (int ks = 0; ks < 2; ++ks) {
                short8v a = *(const short8v*)(xp + ks * 32 + q * 8);
                #pragma unroll
                for (int nt = 0; nt < 4; ++nt)
                    acc[nt] = __builtin_amdgcn_mfma_f32_16x16x32_bf16(
                        a, w1f[ks][nt], acc[nt], 0, 0, 0);
            }
            #pragma unroll
            for (int ks = 2; ks < 4; ++ks) {
                int k0 = (ks - 2) * 32 + q * 8;
                float4 lo = *(const float4*)(ep + k0);
                float4 hi = *(const float4*)(ep + k0 + 4);
                short8v a;
                a[0] = (short)f2bf(lo.x); a[1] = (short)f2bf(lo.y);
                a[2] = (short)f2bf(lo.z); a[3] = (short)f2bf(lo.w);
                a[4] = (short)f2bf(hi.x); a[5] = (short)f2bf(hi.y);
                a[6] = (short)f2bf(hi.z); a[7] = (short)f2bf(hi.w);
                #pragma unroll
                for (int nt = 0; nt < 4; ++nt)
                    acc[nt] = __builtin_amdgcn_mfma_f32_16x16x32_bf16(
                        a, w1f[ks][nt], acc[nt], 0, 0, 0);
            }

            // bias + relu + LN; store m rows as pk dwords (even-c lanes)
            float s1[4] = {0, 0, 0, 0}, s2[4] = {0, 0, 0, 0};
            #pragma unroll
            for (int nt = 0; nt < 4; ++nt)
                #pragma unroll
                for (int r = 0; r < 4; ++r) {
                    float f = fmaxf(acc[nt][r] + b1v[nt], 0.f);
                    acc[nt][r] = f;
                    s1[r] += f; s2[r] += f * f;
                }
            #pragma unroll
            for (int mm = 1; mm <= 8; mm <<= 1)
                #pragma unroll
                for (int r = 0; r < 4; ++r) {
                    s1[r] += __shfl_xor(s1[r], mm);
                    s2[r] += __shfl_xor(s2[r], mm);
                }
            #pragma unroll
            for (int r = 0; r < 4; ++r) {
                float mu = s1[r] * (1.f / 64.f);
                float var = s2[r] * (1.f / 64.f) - mu * mu;
                float rs = rsqrtf(var + EPS);
                long ee = e0 + mt * 16 + q * 4 + r;
                #pragma unroll
                for (int nt = 0; nt < 4; ++nt) {
                    float h = (acc[nt][r] - mu) * rs * g1v[nt] + bev[nt];
                    float nb = __shfl_xor(h, 1);
                    if (ee < E && !(c & 1)) {
                        unsigned pk = (unsigned)f2bf(h) | ((unsigned)f2bf(nb) << 16);
                        *(unsigned*)(m + ee * 64 + nt * 16 + c) = pk;
                    }
                }
            }
        }
    }
}

// ---------------- K2: sorted slot-sweep aggregation; pk-atomic per segment ----------------
// lane = feature. 8-deep batched row loads of m; uniform-branch segment flush.
__global__ __launch_bounds__(256, 8) void agg_kernel(
    const unsigned short* __restrict__ m, const int* __restrict__ perm,
    const int* __restrict__ dsts, unsigned short* __restrict__ summed, int E)
{
    const int lane = threadIdx.x & 63;
    const int wid  = threadIdx.x >> 6;

    for (long s0 = ((long)blockIdx.x * 4 + wid) * 64; s0 < E; s0 += (long)gridDim.x * 256) {
        long sl = s0 + lane;
        int pe_l = (sl < E) ? perm[sl] : 0;
        int dv_l = (sl < E) ? dsts[sl] : -1;

        float acc = 0.f;
        #pragma unroll
        for (int base = 0; base < 64; base += 8) {
            int pe8[8], dv8[8]; float v[8];
            #pragma unroll
            for (int j = 0; j < 8; ++j) {
                pe8[j] = __shfl(pe_l, base + j);
                dv8[j] = __shfl(dv_l, base + j);
            }
            int dvn = (base < 56) ? __shfl(dv_l, base + 8) : (int)0x80000000;
            #pragma unroll
            for (int j = 0; j < 8; ++j)
                v[j] = bf2f(m[(long)pe8[j] * 64 + lane]);
            #pragma unroll
            for (int j = 0; j < 8; ++j) {
                if (dv8[j] >= 0) acc += v[j];
                int nxt = (j < 7) ? dv8[j + 1] : dvn;
                if (nxt != dv8[j]) {                 // wave-uniform branch
                    float nb = __shfl_xor(acc, 1);
                    if (dv8[j] >= 0 && !(lane & 1)) {
                        unsigned pk = (unsigned)f2bf(acc) | ((unsigned)f2bf(nb) << 16);
                        unsigned long long a64 = (unsigned long long)
                            (summed + (long)dv8[j] * 64 + lane);
                        asm volatile("global_atomic_pk_add_bf16 %0, %1, off"
                                     :: "v"(a64), "v"(pk));
                    }
                    acc = 0.f;
                }
            }
        }
    }
}

// ---------------- fallback R9 fused edge kernel ----------------
__global__ __launch_bounds__(256) void edge_kernel_r9(
    const unsigned short* __restrict__ xbf, const float* __restrict__ eattr,
    const int2* __restrict__ einfo, const int* __restrict__ dsts,
    const float* __restrict__ W1, const float* __restrict__ b1,
    const float* __restrict__ g1, const float* __restrict__ be1,
    unsigned short* __restrict__ summed,
    int E, int N)
{
    __shared__ unsigned short T[4][64][72];
    __shared__ int dseg[4][64];

    const int lane = threadIdx.x & 63;
    const int wid  = threadIdx.x >> 6;
    const int c = lane & 15;
    const int q = lane >> 4;

    short8v w1f[4][4];
    #pragma unroll
    for (int ks = 0; ks < 4; ++ks)
        #pragma unroll
        for (int nt = 0; nt < 4; ++nt) {
            int k0 = ks * 32 + q * 8;
            int n  = nt * 16 + c;
            short8v f;
            #pragma unroll
            for (int j = 0; j < 8; ++j) f[j] = (short)f2bf(W1[(k0 + j) * 64 + n]);
            w1f[ks][nt] = f;
        }
    float b1v[4], g1v[4], bev[4];
    #pragma unroll
    for (int nt = 0; nt < 4; ++nt) {
        b1v[nt] = b1[nt * 16 + c];
        g1v[nt] = g1[nt * 16 + c];
        bev[nt] = be1[nt * 16 + c];
    }

    for (long e0 = (long)blockIdx.x * 256 + wid * 64; e0 < E; e0 += (long)gridDim.x * 256) {
        long el = e0 + lane;
        bool valid = el < E;
        int2 ps = valid ? einfo[el] : make_int2(0, 0);
        int pe = ps.x, sv = ps.y;
        int dv = valid ? dsts[el] : -1;

        int prev = __shfl_up(dv, 1);
        int seg  = (lane > 0 && dv != prev) ? 1 : 0;
        int rank = seg;
        #pragma unroll
        for (int d = 1; d < 64; d <<= 1) {
            int v = __shfl_up(rank, d);
            if (lane >= d) rank += v;
        }
        int nseg = __shfl(rank, 63) + 1;
        if (lane == 0 || seg) dseg[wid][rank] = dv;

        #pragma unroll
        for (int mt = 0; mt < 4; ++mt) {
            int src  = __shfl(sv, mt * 16 + c);
            int pidx = __shfl(pe, mt * 16 + c);
            const unsigned short* xp = xbf + (long)src * 64;
            const float* ep = eattr + (long)pidx * 64;

            f32x4 acc[4];
            #pragma unroll
            for (int nt = 0; nt < 4; ++nt) acc[nt] = (f32x4){0.f, 0.f, 0.f, 0.f};

            #pragma unroll
            for (int ks = 0; ks < 2; ++ks) {
                short8v a = *(const short8v*)(xp + ks * 32 + q * 8);
                #pragma unroll
                for (int nt = 0; nt < 4; ++nt)
                    acc[nt] = __builtin_amdgcn_mfma_f32_16x16x32_bf16(
                        a, w1f[ks][nt], acc[nt], 0, 0, 0);
            }
            #pragma unroll
            for (int ks = 2; ks < 4; ++ks) {
                int k0 = (ks - 2) * 32 + q * 8;
                float4 lo = *(const float4*)(ep + k0);
                float4 hi = *(const float4*)(ep + k0 + 4);
                short8v a;
                a[0] = (short)f2bf(lo.x); a[1] = (short)f2bf(lo.y);
                a[2] = (short)f2bf(lo.z); a[3] = (short)f2bf(lo.w);
                a[4] = (short)f2bf(hi.x); a[5] = (short)f2bf(hi.y);
                a[6] = (short)f2bf(hi.z); a[7] = (short)f2bf(hi.w);
                #pragma unroll
                for (int nt = 0; nt < 4; ++nt)
                    acc[nt] = __builtin_amdgcn_mfma_f32_16x16x32_bf16(
                        a, w1f[ks][nt], acc[nt], 0, 0, 0);
            }

            float s1[4] = {0, 0, 0, 0}, s2[4] = {0, 0, 0, 0};
            #pragma unroll
            for (int nt = 0; nt < 4; ++nt)
                #pragma unroll
                for (int r = 0; r < 4; ++r) {
                    float f = fmaxf(acc[nt][r] + b1v[nt], 0.f);
                    acc[nt][r] = f;
                    s1[r] += f; s2[r] += f * f;
                }
            #pragma unroll
            for (int mmm = 1; mmm <= 8; mmm <<= 1)
                #pragma unroll
                for (int r = 0; r < 4; ++r) {
                    s1[r] += __shfl_xor(s1[r], mmm);
                    s2[r] += __shfl_xor(s2[r], mmm);
                }
            #pragma unroll
            for (int r = 0; r < 4; ++r) {
                float mu = s1[r] * (1.f / 64.f);
                float var = s2[r] * (1.f / 64.f) - mu * mu;
                float rs = rsqrtf(var + EPS);
                #pragma unroll
                for (int nt = 0; nt < 4; ++nt) {
                    float h = (acc[nt][r] - mu) * rs * g1v[nt] + bev[nt];
                    T[wid][nt * 16 + c][mt * 16 + q * 4 + r] = f2bf(h);
                }
            }
        }

        short8v bfr[2][4];
        #pragma unroll
        for (int ks = 0; ks < 2; ++ks)
            #pragma unroll
            for (int nt = 0; nt < 4; ++nt)
                bfr[ks][nt] = *(const short8v*)&T[wid][nt * 16 + c][ks * 32 + q * 8];

        const short ONE = (short)0x3F80;
        #pragma unroll
        for (int mt = 0; mt < 4; ++mt) {
            if (mt * 16 < nseg) {
                f32x4 acc2[4];
                #pragma unroll
                for (int nt = 0; nt < 4; ++nt) acc2[nt] = (f32x4){0.f, 0.f, 0.f, 0.f};
                #pragma unroll
                for (int ks = 0; ks < 2; ++ks) {
                    short8v af;
                    #pragma unroll
                    for (int j = 0; j < 8; ++j) {
                        int rk = __shfl(rank, ks * 32 + q * 8 + j);
                        af[j] = (rk == mt * 16 + c) ? ONE : (short)0;
                    }
                    #pragma unroll
                    for (int nt = 0; nt < 4; ++nt)
                        acc2[nt] = __builtin_amdgcn_mfma_f32_16x16x32_bf16(
                            af, bfr[ks][nt], acc2[nt], 0, 0, 0);
                }
                #pragma unroll
                for (int r = 0; r < 4; ++r) {
                    int s = mt * 16 + q * 4 + r;
                    #pragma unroll
                    for (int nt = 0; nt < 4; ++nt) {
                        float val = acc2[nt][r];
                        float nb = __shfl_xor(val, 1);
                        if (s < nseg && !(c & 1)) {
                            int dst = dseg[wid][s];
                            if (dst >= 0) {
                                unsigned pk = (unsigned)f2bf(val) | ((unsigned)f2bf(nb) << 16);
                                unsigned long long a64 = (unsigned long long)
                                    (summed + (long)dst * 64 + nt * 16 + c);
                                asm volatile("global_atomic_pk_add_bf16 %0, %1, off"
                                             :: "v"(a64), "v"(pk));
                            }
                        }
                    }
                }
            }
        }
    }
}

// ---------------- node stage (unchanged) ----------------
__global__ __launch_bounds__(256) void node_kernel(
    const float* __restrict__ x_h, const float* __restrict__ u,
    const float* __restrict__ W2, const float* __restrict__ b2,
    const float* __restrict__ g2, const float* __restrict__ be2,
    const float* __restrict__ W3, const float* __restrict__ b3,
    const float* __restrict__ g3, const float* __restrict__ be3,
    const unsigned short* __restrict__ summed, const int* __restrict__ cnt,
    float* __restrict__ out, int N)
{
    __shared__ unsigned short sh[4][64][72];

    const int lane = threadIdx.x & 63;
    const int wid  = threadIdx.x >> 6;
    const int c = lane & 15;
    const int q = lane >> 4;
    const float u0 = u[0];

    short8v w2f[4][4], w3f[2][4];
    #pragma unroll
    for (int ks = 0; ks < 4; ++ks)
        #pragma unroll
        for (int nt = 0; nt < 4; ++nt) {
            int k0 = ks * 32 + q * 8;
            int n  = nt * 16 + c;
            short8v f;
            #pragma unroll
            for (int j = 0; j < 8; ++j) f[j] = (short)f2bf(W2[(k0 + j) * 64 + n]);
            w2f[ks][nt] = f;
        }
    #pragma unroll
    for (int ks = 0; ks < 2; ++ks)
        #pragma unroll
        for (int nt = 0; nt < 4; ++nt) {
            int k0 = ks * 32 + q * 8;
            int n  = nt * 16 + c;
            short8v f;
            #pragma unroll
            for (int j = 0; j < 8; ++j) f[j] = (short)f2bf(W3[(k0 + j) * 64 + n]);
            w3f[ks][nt] = f;
        }

    float b2p[4], g2v[4], be2v[4], b3v[4], g3v[4], be3v[4];
    #pragma unroll
    for (int nt = 0; nt < 4; ++nt) {
        int n = nt * 16 + c;
        b2p[nt] = b2[n] + u0 * W2[128 * 64 + n];
        g2v[nt] = g2[n]; be2v[nt] = be2[n];
        b3v[nt] = b3[n]; g3v[nt] = g3[n]; be3v[nt] = be3[n];
    }

    const long n0 = ((long)blockIdx.x * 4 + wid) * 64;
    if (n0 >= N) return;

    #pragma unroll
    for (int mt = 0; mt < 4; ++mt) {
        long nr = n0 + mt * 16 + c;
        long nc = (nr < N) ? nr : (N - 1);
        const float* xp = x_h + nc * 64;
        const unsigned short* sp = summed + nc * 64;
        float inv = 1.f / fmaxf((float)cnt[nc], 1.f);

        f32x4 acc[4];
        #pragma unroll
        for (int nt = 0; nt < 4; ++nt) acc[nt] = (f32x4){0.f, 0.f, 0.f, 0.f};

        #pragma unroll
        for (int ks = 0; ks < 4; ++ks) {
            int k0 = ks * 32 + q * 8;
            short8v a;
            if (ks < 2) {
                float4 lo = *(const float4*)(xp + k0);
                float4 hi = *(const float4*)(xp + k0 + 4);
                a[0] = (short)f2bf(lo.x); a[1] = (short)f2bf(lo.y);
                a[2] = (short)f2bf(lo.z); a[3] = (short)f2bf(lo.w);
                a[4] = (short)f2bf(hi.x); a[5] = (short)f2bf(hi.y);
                a[6] = (short)f2bf(hi.z); a[7] = (short)f2bf(hi.w);
            } else {
                short8v raw = *(const short8v*)(sp + (k0 - 64));
                #pragma unroll
                for (int j = 0; j < 8; ++j)
                    a[j] = (short)f2bf(bf2f((unsigned short)raw[j]) * inv);
            }
            #pragma unroll
            for (int nt = 0; nt < 4; ++nt)
                acc[nt] = __builtin_amdgcn_mfma_f32_16x16x32_bf16(a, w2f[ks][nt], acc[nt], 0, 0, 0);
        }

        float s1[4] = {0, 0, 0, 0}, s2[4] = {0, 0, 0, 0};
        #pragma unroll
        for (int nt = 0; nt < 4; ++nt)
            #pragma unroll
            for (int r = 0; r < 4; ++r) {
                float f = fmaxf(acc[nt][r] + b2p[nt], 0.f);
                acc[nt][r] = f;
                s1[r] += f; s2[r] += f * f;
            }
        #pragma unroll
        for (int mm = 1; mm <= 8; mm <<= 1)
            #pragma unroll
            for (int r = 0; r < 4; ++r) {
                s1[r] += __shfl_xor(s1[r], mm);
                s2[r] += __shfl_xor(s2[r], mm);
            }
        #pragma unroll
        for (int r = 0; r < 4; ++r) {
            float mu = s1[r] * (1.f / 64.f);
            float var = s2[r] * (1.f / 64.f) - mu * mu;
            float rs = rsqrtf(var + EPS);
            #pragma unroll
            for (int nt = 0; nt < 4; ++nt) {
                float h2 = (acc[nt][r] - mu) * rs * g2v[nt] + be2v[nt];
                sh[wid][mt * 16 + q * 4 + r][nt * 16 + c] = f2bf(h2);
            }
        }
    }

    #pragma unroll
    for (int mt = 0; mt < 4; ++mt) {
        f32x4 acc[4];
        #pragma unroll
        for (int nt = 0; nt < 4; ++nt) acc[nt] = (f32x4){0.f, 0.f, 0.f, 0.f};

        #pragma unroll
        for (int ks = 0; ks < 2; ++ks) {
            short8v a = *(const short8v*)&sh[wid][mt * 16 + c][ks * 32 + q * 8];
            #pragma unroll
            for (int nt = 0; nt < 4; ++nt)
                acc[nt] = __builtin_amdgcn_mfma_f32_16x16x32_bf16(a, w3f[ks][nt], acc[nt], 0, 0, 0);
        }

        float s1[4] = {0, 0, 0, 0}, s2[4] = {0, 0, 0, 0};
        #pragma unroll
        for (int nt = 0; nt < 4; ++nt)
            #pragma unroll
            for (int r = 0; r < 4; ++r) {
                float f = acc[nt][r] + b3v[nt];
                acc[nt][r] = f;
                s1[r] += f; s2[r] += f * f;
            }
        #pragma unroll
        for (int mm = 1; mm <= 8; mm <<= 1)
            #pragma unroll
            for (int r = 0; r < 4; ++r) {
                s1[r] += __shfl_xor(s1[r], mm);
                s2[r] += __shfl_xor(s2[r], mm);
            }
        #pragma unroll
        for (int r = 0; r < 4; ++r) {
            float mu = s1[r] * (1.f / 64.f);
            float var = s2[r] * (1.f / 64.f) - mu * mu;
            float rs = rsqrtf(var + EPS);
            long node = n0 + mt * 16 + q * 4 + r;
            if (node < N) {
                #pragma unroll
                for (int nt = 0; nt < 4; ++nt) {
                    long off = node * 64 + nt * 16 + c;
                    float h3 = (acc[nt][r] - mu) * rs * g3v[nt] + be3v[nt];
                    out[off] = h3 + x_h[off];
                }
            }
        }
    }
}

extern "C" void kernel_launch(void* const* d_in, const int* in_sizes, int n_in,
                              void* d_out, int out_size, void* d_ws, size_t ws_size,
                              hipStream_t stream)
{
    const float* x_h   = (const float*)d_in[0];
    const int*   eidx  = (const int*)  d_in[1];
    const float* eattr = (const float*)d_in[2];
    const float* u     = (const float*)d_in[3];
    // d_in[4] = batch (all zeros, B=1) -> unused
    const float* W1  = (const float*)d_in[5];
    const float* b1  = (const float*)d_in[6];
    const float* g1  = (const float*)d_in[7];
    const float* be1 = (const float*)d_in[8];
    const float* W2  = (const float*)d_in[9];
    const float* b2  = (const float*)d_in[10];
    const float* g2  = (const float*)d_in[11];
    const float* be2 = (const float*)d_in[12];
    const float* W3  = (const float*)d_in[13];
    const float* b3  = (const float*)d_in[14];
    const float* g3  = (const float*)d_in[15];
    const float* be3 = (const float*)d_in[16];

    const int N = in_sizes[0] / 64;
    const int E = in_sizes[1] / 2;
    const int* row = eidx;
    const int* col = eidx + E;

    size_t need = (size_t)N * 268 + (size_t)E * 8 + (size_t)E * 128 + 4096;

    if (ws_size >= need) {
        // ---- new path: K1 (natural-order mlp -> m) + K2 (sorted aggregation) ----
        char* w = (char*)d_ws;
        unsigned short* xbf    = (unsigned short*)w;   w += (size_t)N * 128;
        unsigned short* summed = (unsigned short*)w;   w += (size_t)N * 128;
        int* cnt      = (int*)w;                       w += (size_t)N * 4;
        int* offs     = (int*)w;                       w += (size_t)N * 4;
        int* head     = (int*)w;                       w += (size_t)N * 4;
        int* perm     = (int*)w;                       w += (size_t)E * 4;
        int* dsts     = (int*)w;                       w += (size_t)E * 4;
        unsigned short* m = (unsigned short*)w;        w += (size_t)E * 128;
        int* partials = (int*)w;

        prep_kernel<<<1024, 256, 0, stream>>>(x_h, xbf, (float*)summed,
                                              ((long)N * 33) / 4, (long)N * 8);
        mlp_kernel<<<2048, 256, 0, stream>>>(xbf, eidx, eattr, W1, b1, g1, be1,
                                             m, cnt, E);
        int sblocks = (N + 1023) / 1024;
        scan1_kernel<<<sblocks, 256, 0, stream>>>(cnt, offs, partials, N);
        scan2_kernel<<<1, 256, 0, stream>>>(partials, sblocks);
        scan3_kernel<<<sblocks, 256, 0, stream>>>(offs, head, partials, N);
        permscat2_kernel<<<2048, 256, 0, stream>>>(col, head, perm, dsts, E);
        agg_kernel<<<2048, 256, 0, stream>>>(m, perm, dsts, summed, E);

        int nblocks = (N + 255) / 256;
        node_kernel<<<nblocks, 256, 0, stream>>>(x_h, u, W2, b2, g2, be2, W3, b3, g3, be3,
                                                 summed, cnt, (float*)d_out, N);
    } else {
        // ---- fallback: R9 fused path ----
        char* w = (char*)d_ws;
        unsigned short* xbf    = (unsigned short*)w;   w += (size_t)N * 128;
        unsigned short* summed = (unsigned short*)w;   w += (size_t)N * 128;
        int* cnt      = (int*)w;                       w += (size_t)N * 4;
        int* offs     = (int*)w;                       w += (size_t)N * 4;
        int* head     = (int*)w;                       w += (size_t)N * 4;
        int* dsts     = (int*)w;                       w += (size_t)E * 4;
        int2* einfo   = (int2*)w;                      w += (size_t)E * 8;
        int* partials = (int*)w;

        prep_kernel<<<1024, 256, 0, stream>>>(x_h, xbf, (float*)summed,
                                              ((long)N * 33) / 4, (long)N * 8);
        hist_kernel<<<2048, 256, 0, stream>>>(col, cnt, E);
        int sblocks = (N + 1023) / 1024;
        scan1_kernel<<<sblocks, 256, 0, stream>>>(cnt, offs, partials, N);
        scan2_kernel<<<1, 256, 0, stream>>>(partials, sblocks);
        scan3_kernel<<<sblocks, 256, 0, stream>>>(offs, head, partials, N);
        permscat_r9_kernel<<<2048, 256, 0, stream>>>(row, col, head, einfo, dsts, E);

        int tiles = (E + 63) / 64;
        int eblocks = (tiles + 7) / 8;
        edge_kernel_r9<<<eblocks, 256, 0, stream>>>(xbf, eattr, einfo, dsts,
                                                    W1, b1, g1, be1, summed, E, N);
        int nblocks = (N + 255) / 256;
        node_kernel<<<nblocks, 256, 0, stream>>>(x_h, u, W2, b2, g2, be2, W3, b3, g3, be3,
                                                 summed, cnt, (float*)d_out, N);
    }
}